// Round 10
// baseline (567.787 us; speedup 1.0000x reference)
//
#include <hip/hip_runtime.h>

#define IC 4096
typedef unsigned short u16;
typedef unsigned int   u32;
typedef float f32x2 __attribute__((ext_vector_type(2)));

static __device__ __forceinline__ u16 f2h(float f) {
    _Float16 h = (_Float16)f;               // RNE
    u16 r; __builtin_memcpy(&r, &h, 2); return r;
}
static __device__ __forceinline__ float h2f(u16 h) {
    _Float16 x; __builtin_memcpy(&x, &h, 2); return (float)x;
}
// CDNA packed fp32 (VOP3P): 2 f32 FMAs per instruction, full rate.
// Operands are even-aligned VGPR pairs -- ext_vector_type(2) with "v"
// constraint gives exactly that.
static __device__ __forceinline__ f32x2 pk_mul(f32x2 a, f32x2 b) {
    f32x2 d; asm("v_pk_mul_f32 %0, %1, %2" : "=v"(d) : "v"(a), "v"(b)); return d;
}
static __device__ __forceinline__ f32x2 pk_fma(f32x2 a, f32x2 b, f32x2 c) {
    f32x2 d; asm("v_pk_fma_f32 %0, %1, %2, %3" : "=v"(d) : "v"(a), "v"(b), "v"(c)); return d;
}

// ---------------- primary path: dense partials, no atomics ----------------
// Grid = 1024 blocks: (i-chunk 0..511) x (b-half). Block = 8 waves = 8 i,
// loops 128 b. u-contraction runs on packed fp32: pairs along c, so both
// x-pairs (contiguous x[8]) and W c-pairs (contiguous 32-float row) are
// naturally adjacent -- no broadcasts. Softmax logits carry the folded
// log2e so exp is a single native v_exp_f32 (exp2).
template<int USEV, int P16>
__global__ __launch_bounds__(512)
void caps_pass_part(const float* __restrict__ x, const float* __restrict__ W,
                    const float* __restrict__ vprev, void* __restrict__ part)
{
    __shared__ float lds[8][4][256];
    const int tid  = threadIdx.x;
    const int wu   = __builtin_amdgcn_readfirstlane(tid >> 6);  // wave 0..7
    const int lane = tid & 63;
    const int a    = lane >> 2;   // capsule 0..15
    const int dq   = lane & 3;    // d-quad: lane owns d = dq*4..dq*4+3
    const int ib   = (int)blockIdx.x & 511;   // i-chunk
    const int bh   = (int)blockIdx.x >> 9;    // b-half
    const int i    = ib * 8 + wu;             // this wave's i

    // W cache as 16 packed c-pairs: wq[d*4+k] = (W[d, 2k], W[d, 2k+1]).
    // 32 floats pinned -- the proven-safe residency size (r7/r8).
    f32x2 wq[16];
    {
        const f32x2* wp2 = (const f32x2*)(W + ((size_t)a * IC + i) * 128 + dq * 32);
#pragma unroll
        for (int k = 0; k < 16; ++k) wq[k] = wp2[k];
    }
#pragma unroll
    for (int k = 0; k < 16; ++k) asm volatile("" : "+v"(wq[k]));  // no remat

    const int b0 = bh * 128;
    const float SM_SCALE = 4096.0f * 1.44269504088896f;  // logits in log2 units

    for (int ph = 0; ph < 32; ++ph) {
        // prefetch the 4 b's inputs (independent; compiler schedules)
        f32x2 xq[4][4]; float4 va[4];
#pragma unroll
        for (int nb = 0; nb < 4; ++nb) {
            const int b = b0 + ph * 4 + nb;
            const f32x2* xp2 = (const f32x2*)(x + ((size_t)b * IC + i) * 8);
            xq[nb][0] = xp2[0]; xq[nb][1] = xp2[1];
            xq[nb][2] = xp2[2]; xq[nb][3] = xp2[3];
            if (USEV)
                va[nb] = *(const float4*)(vprev + (((size_t)b * 16 + a) * 16 + dq * 4));
        }
#pragma unroll
        for (int nb = 0; nb < 4; ++nb) {
            // u[d] for the lane's 4 d's: 4 pk_mul + 12 pk_fma + 4 horizontal adds
            f32x2 a0 = pk_mul(xq[nb][0], wq[0]);
            f32x2 a1 = pk_mul(xq[nb][0], wq[4]);
            f32x2 a2 = pk_mul(xq[nb][0], wq[8]);
            f32x2 a3 = pk_mul(xq[nb][0], wq[12]);
            a0 = pk_fma(xq[nb][1], wq[1],  a0);
            a1 = pk_fma(xq[nb][1], wq[5],  a1);
            a2 = pk_fma(xq[nb][1], wq[9],  a2);
            a3 = pk_fma(xq[nb][1], wq[13], a3);
            a0 = pk_fma(xq[nb][2], wq[2],  a0);
            a1 = pk_fma(xq[nb][2], wq[6],  a1);
            a2 = pk_fma(xq[nb][2], wq[10], a2);
            a3 = pk_fma(xq[nb][2], wq[14], a3);
            a0 = pk_fma(xq[nb][3], wq[3],  a0);
            a1 = pk_fma(xq[nb][3], wq[7],  a1);
            a2 = pk_fma(xq[nb][3], wq[11], a2);
            a3 = pk_fma(xq[nb][3], wq[15], a3);
            const float u0 = a0.x + a0.y;
            const float u1 = a1.x + a1.y;
            const float u2 = a2.x + a2.y;
            const float u3 = a3.x + a3.y;
            float cw;
            if (USEV == 0) {
                cw = 1.0f / 16.0f;
            } else {
                // agree = u . vprev  (vprev = v1, or v1+v2 for the last pass)
                float ag = u0 * va[nb].x + u1 * va[nb].y
                         + u2 * va[nb].z + u3 * va[nb].w;
                ag += __shfl_xor(ag, 1);   // combine d-quads within the a-group
                ag += __shfl_xor(ag, 2);
                const float blog2 = SM_SCALE * ag;   // log2-domain logits
                // softmax over 16 capsules (4-lane groups); strides 4..32 keep
                // lane bits 0-1 fixed, so replicated values fold once per a.
                float m = blog2;
                m = fmaxf(m, __shfl_xor(m, 4));
                m = fmaxf(m, __shfl_xor(m, 8));
                m = fmaxf(m, __shfl_xor(m, 16));
                m = fmaxf(m, __shfl_xor(m, 32));
                const float e = __builtin_amdgcn_exp2f(blog2 - m);  // v_exp_f32
                float sum = e;
                sum += __shfl_xor(sum, 4);
                sum += __shfl_xor(sum, 8);
                sum += __shfl_xor(sum, 16);
                sum += __shfl_xor(sum, 32);
                cw = __fdividef(e, sum);
            }
            // straight to LDS (ds_write_b128: measured conflict-free r1-r8)
            float4 r;
            r.x = cw * u0; r.y = cw * u1; r.z = cw * u2; r.w = cw * u3;
            *(float4*)&lds[wu][nb][lane * 4] = r;
        }
        __syncthreads();
        if (tid < 256) {
            const int bsel = tid >> 6;          // 0..3
            const int ad4  = (tid & 63) * 4;    // 0..252
            float4 acc = make_float4(0.f, 0.f, 0.f, 0.f);
#pragma unroll
            for (int wv = 0; wv < 8; ++wv) {
                const float4 f = *(const float4*)&lds[wv][bsel][ad4];
                acc.x += f.x; acc.y += f.y; acc.z += f.z; acc.w += f.w;
            }
            const size_t off = (size_t)(ph * 4 + bsel) * 256 + ad4;  // local b * 256
            if (P16) {
                ushort4 pk;
                pk.x = f2h(acc.x); pk.y = f2h(acc.y);
                pk.z = f2h(acc.z); pk.w = f2h(acc.w);
                *(ushort4*)((u16*)part + (size_t)blockIdx.x * 32768 + off) = pk;
            } else {
                *(float4*)((float*)part + (size_t)blockIdx.x * 32768 + off) = acc;
            }
        }
        __syncthreads();
    }
}

// Fused 512-deep partial reduction + squash. Thread = (b, a, d-pair):
// 32768 threads; d-norm via shfl_xor over the 8 d-pair lanes.
template<int ADDP, int P16>
__global__ __launch_bounds__(256)
void caps_squash_part(const void* __restrict__ part, float* __restrict__ vout,
                      const float* __restrict__ vprev)
{
    const int gt = (int)blockIdx.x * 256 + (int)threadIdx.x;  // 0..32767
    const int b  = gt >> 7;
    const int r  = gt & 127;                                  // a*8 + dpair
    const int h  = b >> 7;                                    // b-half
    const int lb = b & 127;                                   // local b in tile
    float f0 = 0.f, f1 = 0.f;
    if (P16) {
        const u32* pp = (const u32*)part + ((size_t)h * 512) * 16384
                      + (size_t)lb * 128 + r;
#pragma unroll 8
        for (int ic = 0; ic < 512; ++ic) {
            const u32 raw = pp[(size_t)ic * 16384];
            f0 += h2f((u16)(raw & 0xffffu));
            f1 += h2f((u16)(raw >> 16));
        }
    } else {
        const float* pp = (const float*)part + ((size_t)h * 512) * 32768
                        + (size_t)lb * 256 + r * 2;
#pragma unroll 8
        for (int ic = 0; ic < 512; ++ic) {
            const float2 v = *(const float2*)(pp + (size_t)ic * 32768);
            f0 += v.x; f1 += v.y;
        }
    }
    float sq = f0 * f0 + f1 * f1;
    sq += __shfl_xor(sq, 1);
    sq += __shfl_xor(sq, 2);
    sq += __shfl_xor(sq, 4);
    const float scale = sq / ((1.0f + sq) * sqrtf(sq + 1e-7f));
    float o0 = f0 * scale, o1 = f1 * scale;
    if (ADDP) {
        const float2 p = *(const float2*)(vprev + (size_t)b * 256 + r * 2);
        o0 += p.x; o1 += p.y;
    }
    *(float2*)(vout + (size_t)b * 256 + r * 2) = make_float2(o0, o1);
}

// ---------------- legacy fallback (round-4, known-good) ----------------
template<int USEV>
__global__ __launch_bounds__(512)
void legacy_pass(const float* __restrict__ x, const float* __restrict__ W,
                 const float* __restrict__ vprev, float* __restrict__ s_rep,
                 int n_rep)
{
    __shared__ float lds[8][4][256];
    const int tid  = threadIdx.x;
    const int wu   = __builtin_amdgcn_readfirstlane(tid >> 6);
    const int lane = tid & 63;
    const int a    = lane >> 2;
    const int dq   = lane & 3;
    const int ichunk = (int)blockIdx.x >> 1;
    const int bhalf  = (int)blockIdx.x & 1;
    const int i0 = ichunk * 32 + wu * 4;
    const int rep = (int)blockIdx.x & (n_rep - 1);
    float* srep = s_rep + (size_t)rep * 65536;

    float w[4][32];
#pragma unroll
    for (int ii = 0; ii < 4; ++ii) {
        const float* wp = W + ((size_t)a * IC + (size_t)(i0 + ii)) * 128 + dq * 32;
#pragma unroll
        for (int q = 0; q < 8; ++q) {
            const float4 f = *(const float4*)(wp + q * 4);
            w[ii][q*4+0]=f.x; w[ii][q*4+1]=f.y; w[ii][q*4+2]=f.z; w[ii][q*4+3]=f.w;
        }
    }
#pragma unroll
    for (int ii = 0; ii < 4; ++ii)
#pragma unroll
        for (int k = 0; k < 32; ++k) asm volatile("" : "+v"(w[ii][k]));

    const int b0 = bhalf * 128;
    for (int ph = 0; ph < 32; ++ph) {
        float sl[4][4];
#pragma unroll
        for (int nb = 0; nb < 4; ++nb) {
            sl[nb][0]=0.f; sl[nb][1]=0.f; sl[nb][2]=0.f; sl[nb][3]=0.f;
            const int b = b0 + ph * 4 + nb;
            float4 va;
            if (USEV)
                va = *(const float4*)(vprev + (((size_t)b * 16 + a) * 16 + dq * 4));
#pragma unroll
            for (int ii = 0; ii < 4; ++ii) {
                const float* xp = x + ((size_t)b * IC + (size_t)(i0 + ii)) * 8;
                const float4 xa = *(const float4*)(xp);
                const float4 xb = *(const float4*)(xp + 4);
                float u0, u1, u2, u3;
                u0 = xa.x * w[ii][0];  u1 = xa.x * w[ii][8];
                u2 = xa.x * w[ii][16]; u3 = xa.x * w[ii][24];
                u0 = fmaf(xa.y, w[ii][1],  u0); u1 = fmaf(xa.y, w[ii][9],  u1);
                u2 = fmaf(xa.y, w[ii][17], u2); u3 = fmaf(xa.y, w[ii][25], u3);
                u0 = fmaf(xa.z, w[ii][2],  u0); u1 = fmaf(xa.z, w[ii][10], u1);
                u2 = fmaf(xa.z, w[ii][18], u2); u3 = fmaf(xa.z, w[ii][26], u3);
                u0 = fmaf(xa.w, w[ii][3],  u0); u1 = fmaf(xa.w, w[ii][11], u1);
                u2 = fmaf(xa.w, w[ii][19], u2); u3 = fmaf(xa.w, w[ii][27], u3);
                u0 = fmaf(xb.x, w[ii][4],  u0); u1 = fmaf(xb.x, w[ii][12], u1);
                u2 = fmaf(xb.x, w[ii][20], u2); u3 = fmaf(xb.x, w[ii][28], u3);
                u0 = fmaf(xb.y, w[ii][5],  u0); u1 = fmaf(xb.y, w[ii][13], u1);
                u2 = fmaf(xb.y, w[ii][21], u2); u3 = fmaf(xb.y, w[ii][29], u3);
                u0 = fmaf(xb.z, w[ii][6],  u0); u1 = fmaf(xb.z, w[ii][14], u1);
                u2 = fmaf(xb.z, w[ii][22], u2); u3 = fmaf(xb.z, w[ii][30], u3);
                u0 = fmaf(xb.w, w[ii][7],  u0); u1 = fmaf(xb.w, w[ii][15], u1);
                u2 = fmaf(xb.w, w[ii][23], u2); u3 = fmaf(xb.w, w[ii][31], u3);
                float cw;
                if (USEV == 0) {
                    cw = 1.0f / 16.0f;
                } else {
                    float ag = u0*va.x + u1*va.y + u2*va.z + u3*va.w;
                    ag += __shfl_xor(ag, 1);
                    ag += __shfl_xor(ag, 2);
                    const float blog = 4096.0f * ag;
                    float m = blog;
                    m = fmaxf(m, __shfl_xor(m, 4));
                    m = fmaxf(m, __shfl_xor(m, 8));
                    m = fmaxf(m, __shfl_xor(m, 16));
                    m = fmaxf(m, __shfl_xor(m, 32));
                    const float e = __expf(blog - m);
                    float sum = e;
                    sum += __shfl_xor(sum, 4);
                    sum += __shfl_xor(sum, 8);
                    sum += __shfl_xor(sum, 16);
                    sum += __shfl_xor(sum, 32);
                    cw = __fdividef(e, sum);
                }
                sl[nb][0] = fmaf(cw, u0, sl[nb][0]);
                sl[nb][1] = fmaf(cw, u1, sl[nb][1]);
                sl[nb][2] = fmaf(cw, u2, sl[nb][2]);
                sl[nb][3] = fmaf(cw, u3, sl[nb][3]);
            }
        }
#pragma unroll
        for (int nb = 0; nb < 4; ++nb)
            *(float4*)&lds[wu][nb][lane * 4] =
                make_float4(sl[nb][0], sl[nb][1], sl[nb][2], sl[nb][3]);
        __syncthreads();
        if (tid < 256) {
            const int bsel = tid >> 6;
            const int ad4  = (tid & 63) * 4;
            float4 acc = make_float4(0.f, 0.f, 0.f, 0.f);
#pragma unroll
            for (int wv = 0; wv < 8; ++wv) {
                const float4 f = *(const float4*)&lds[wv][bsel][ad4];
                acc.x += f.x; acc.y += f.y; acc.z += f.z; acc.w += f.w;
            }
            float* dst = srep + (size_t)(b0 + ph * 4 + bsel) * 256 + ad4;
            unsafeAtomicAdd(dst + 0, acc.x);
            unsafeAtomicAdd(dst + 1, acc.y);
            unsafeAtomicAdd(dst + 2, acc.z);
            unsafeAtomicAdd(dst + 3, acc.w);
        }
        __syncthreads();
    }
}

template<int ADDP, int ZERO>
__global__ void legacy_squash(float* __restrict__ srep, int n_rep,
                              float* __restrict__ vout, const float* __restrict__ vprev)
{
    const int t = (int)blockIdx.x * 256 + (int)threadIdx.x;
    float4 f0 = make_float4(0.f,0.f,0.f,0.f), f1 = f0, f2 = f0, f3 = f0;
    for (int r = 0; r < n_rep; ++r) {
        float* sp = srep + (size_t)r * 65536 + (size_t)t * 16;
        const float4 a0 = *(const float4*)(sp + 0);
        const float4 a1 = *(const float4*)(sp + 4);
        const float4 a2 = *(const float4*)(sp + 8);
        const float4 a3 = *(const float4*)(sp + 12);
        f0.x+=a0.x; f0.y+=a0.y; f0.z+=a0.z; f0.w+=a0.w;
        f1.x+=a1.x; f1.y+=a1.y; f1.z+=a1.z; f1.w+=a1.w;
        f2.x+=a2.x; f2.y+=a2.y; f2.z+=a2.z; f2.w+=a2.w;
        f3.x+=a3.x; f3.y+=a3.y; f3.z+=a3.z; f3.w+=a3.w;
        if (ZERO) {
            const float4 z = make_float4(0.f,0.f,0.f,0.f);
            *(float4*)(sp+0)=z; *(float4*)(sp+4)=z; *(float4*)(sp+8)=z; *(float4*)(sp+12)=z;
        }
    }
    float sq = f0.x*f0.x+f0.y*f0.y+f0.z*f0.z+f0.w*f0.w
             + f1.x*f1.x+f1.y*f1.y+f1.z*f1.z+f1.w*f1.w
             + f2.x*f2.x+f2.y*f2.y+f2.z*f2.z+f2.w*f2.w
             + f3.x*f3.x+f3.y*f3.y+f3.z*f3.z+f3.w*f3.w;
    const float scale = sq / ((1.0f + sq) * sqrtf(sq + 1e-7f));
    float4 o0, o1, o2, o3;
    o0.x=f0.x*scale; o0.y=f0.y*scale; o0.z=f0.z*scale; o0.w=f0.w*scale;
    o1.x=f1.x*scale; o1.y=f1.y*scale; o1.z=f1.z*scale; o1.w=f1.w*scale;
    o2.x=f2.x*scale; o2.y=f2.y*scale; o2.z=f2.z*scale; o2.w=f2.w*scale;
    o3.x=f3.x*scale; o3.y=f3.y*scale; o3.z=f3.z*scale; o3.w=f3.w*scale;
    if (ADDP) {
        const float* pp = vprev + (size_t)t * 16;
        const float4 p0 = *(const float4*)(pp + 0);
        const float4 p1 = *(const float4*)(pp + 4);
        const float4 p2 = *(const float4*)(pp + 8);
        const float4 p3 = *(const float4*)(pp + 12);
        o0.x+=p0.x; o0.y+=p0.y; o0.z+=p0.z; o0.w+=p0.w;
        o1.x+=p1.x; o1.y+=p1.y; o1.z+=p1.z; o1.w+=p1.w;
        o2.x+=p2.x; o2.y+=p2.y; o2.z+=p2.z; o2.w+=p2.w;
        o3.x+=p3.x; o3.y+=p3.y; o3.z+=p3.z; o3.w+=p3.w;
    }
    float* vp = vout + (size_t)t * 16;
    *(float4*)(vp+0)=o0; *(float4*)(vp+4)=o1; *(float4*)(vp+8)=o2; *(float4*)(vp+12)=o3;
}

__global__ void legacy_zero(float* __restrict__ p)
{
    *(float4*)(p + ((size_t)blockIdx.x * 256 + threadIdx.x) * 4) =
        make_float4(0.f, 0.f, 0.f, 0.f);
}

extern "C" void kernel_launch(void* const* d_in, const int* in_sizes, int n_in,
                              void* d_out, int out_size, void* d_ws, size_t ws_size,
                              hipStream_t stream)
{
    const float* x = (const float*)d_in[0];   // [256, 4096, 8]
    const float* W = (const float*)d_in[1];   // [16, 4096, 16, 8]
    float* out = (float*)d_out;               // [256, 16, 16]

    // partial storage: 1024 tiles x 32768 elements
    const size_t need16 = (size_t)1024 * 32768 * 2 + 2 * 65536 * 4;  // 64.5 MiB
    const size_t need32 = (size_t)1024 * 32768 * 4 + 2 * 65536 * 4;  // 128.5 MiB

    if (ws_size >= need16) {
        // fp16 partials: 8x finer mantissa than the bf16 that failed r6 at
        // 2.1e-2; predicted ~2.7e-3 vs 1.7e-2 threshold. Halves partial BW.
        u16*  part = (u16*)d_ws;
        float* v1  = (float*)((char*)d_ws + (size_t)1024 * 32768 * 2);
        float* vs  = v1 + 65536;
        caps_pass_part<0, 1><<<1024, 512, 0, stream>>>(x, W, nullptr, part);
        caps_squash_part<0, 1><<<128, 256, 0, stream>>>(part, v1, nullptr);
        caps_pass_part<1, 1><<<1024, 512, 0, stream>>>(x, W, v1, part);
        caps_squash_part<1, 1><<<128, 256, 0, stream>>>(part, vs, v1);
        caps_pass_part<1, 1><<<1024, 512, 0, stream>>>(x, W, vs, part);
        caps_squash_part<0, 1><<<128, 256, 0, stream>>>(part, out, nullptr);
    } else if (ws_size >= need32) {
        float* part = (float*)d_ws;
        float* v1   = part + (size_t)1024 * 32768;
        float* vs   = v1 + 65536;
        caps_pass_part<0, 0><<<1024, 512, 0, stream>>>(x, W, nullptr, part);
        caps_squash_part<0, 0><<<128, 256, 0, stream>>>(part, v1, nullptr);
        caps_pass_part<1, 0><<<1024, 512, 0, stream>>>(x, W, v1, part);
        caps_squash_part<1, 0><<<128, 256, 0, stream>>>(part, vs, v1);
        caps_pass_part<1, 0><<<1024, 512, 0, stream>>>(x, W, vs, part);
        caps_squash_part<0, 0><<<128, 256, 0, stream>>>(part, out, nullptr);
    } else {
        int R = 1;
        if (ws_size >= (size_t)(8 + 2) * 65536 * 4) R = 8;
        else if (ws_size >= (size_t)(2 + 2) * 65536 * 4) R = 2;
        float* srep = (float*)d_ws;
        float* v1   = srep + (size_t)R * 65536;
        float* vs   = v1 + 65536;
        legacy_zero<<<R * 64, 256, 0, stream>>>(srep);
        legacy_pass<0><<<256, 512, 0, stream>>>(x, W, nullptr, srep, R);
        legacy_squash<0, 1><<<16, 256, 0, stream>>>(srep, R, v1, nullptr);
        legacy_pass<1><<<256, 512, 0, stream>>>(x, W, v1, srep, R);
        legacy_squash<1, 1><<<16, 256, 0, stream>>>(srep, R, vs, v1);
        legacy_pass<1><<<256, 512, 0, stream>>>(x, W, vs, srep, R);
        legacy_squash<0, 0><<<16, 256, 0, stream>>>(srep, R, out, nullptr);
    }
}

// Round 12
// 513.090 us; speedup vs baseline: 1.1066x; 1.1066x over previous
//
#include <hip/hip_runtime.h>

#define IC 4096
typedef unsigned short u16;
typedef unsigned int   u32;
typedef __fp16 h2 __attribute__((ext_vector_type(2)));   // matches cvt_pkrtz return type

static __device__ __forceinline__ u32 pack_rtz(float a, float b) {
    h2 h = __builtin_amdgcn_cvt_pkrtz(a, b);   // v_cvt_pkrtz_f16_f32
    u32 u; __builtin_memcpy(&u, &h, 4); return u;
}
static __device__ __forceinline__ float h2lo(u32 r) {
    h2 h; __builtin_memcpy(&h, &r, 4); return (float)h.x;
}
static __device__ __forceinline__ float h2hi(u32 r) {
    h2 h; __builtin_memcpy(&h, &r, 4); return (float)h.y;
}

// ---------------- primary path: fp16 partials, 1 barrier/phase ----------------
// Grid = 1024 blocks: (i-chunk 0..511) x (b-half). Block = 8 waves = 8 i,
// loops 128 b in 32 phases of 4. Double-buffered fp16 LDS tile: compute
// phase p+1 into buf[(p+1)&1] while reducing buf[p&1]; ONE barrier per phase
// (r8-r10 had two). Scalar fmaf chains (v_pk_fma_f32 is NOT double-rate on
// CDNA4 -- r10 regression). Softmax in log2 domain (native v_exp_f32).
template<int USEV>
__global__ __launch_bounds__(512)
void caps_pass_part(const float* __restrict__ x, const float* __restrict__ W,
                    const float* __restrict__ vprev, u32* __restrict__ part)
{
    __shared__ u32 lds2[2][8][4][128];   // [buf][wave][nb][u32 col] = 16 KB
    const int tid  = threadIdx.x;
    const int wu   = __builtin_amdgcn_readfirstlane(tid >> 6);  // wave 0..7
    const int lane = tid & 63;
    const int a    = lane >> 2;   // capsule 0..15
    const int dq   = lane & 3;    // d-quad: lane owns d = dq*4..dq*4+3
    const int ib   = (int)blockIdx.x & 511;   // i-chunk
    const int bh   = (int)blockIdx.x >> 9;    // b-half
    const int i    = ib * 8 + wu;             // this wave's i

    // W cache: 32 floats/lane -- the proven-safe residency size (r7-r10).
    float w[32];
    {
        const float* wp = W + ((size_t)a * IC + i) * 128 + dq * 32;
#pragma unroll
        for (int q = 0; q < 8; ++q) {
            const float4 f = *(const float4*)(wp + q * 4);
            w[q*4+0] = f.x; w[q*4+1] = f.y; w[q*4+2] = f.z; w[q*4+3] = f.w;
        }
    }
#pragma unroll
    for (int k = 0; k < 32; ++k) asm volatile("" : "+v"(w[k]));  // no remat

    const int b0 = bh * 128;
    const float SM_SCALE = 4096.0f * 1.44269504088896f;  // logits in log2 units

    auto compute_phase = [&](int ph, int buf) {
        float4 xa[4], xb[4], va[4];
#pragma unroll
        for (int nb = 0; nb < 4; ++nb) {
            const int b = b0 + ph * 4 + nb;
            const float* xp = x + ((size_t)b * IC + i) * 8;   // wave-uniform
            xa[nb] = *(const float4*)(xp);
            xb[nb] = *(const float4*)(xp + 4);
            if (USEV)
                va[nb] = *(const float4*)(vprev + (((size_t)b * 16 + a) * 16 + dq * 4));
        }
#pragma unroll
        for (int nb = 0; nb < 4; ++nb) {
            float u0, u1, u2, u3;
            u0 = xa[nb].x * w[0];
            u1 = xa[nb].x * w[8];
            u2 = xa[nb].x * w[16];
            u3 = xa[nb].x * w[24];
            u0 = fmaf(xa[nb].y, w[1],  u0); u1 = fmaf(xa[nb].y, w[9],  u1);
            u2 = fmaf(xa[nb].y, w[17], u2); u3 = fmaf(xa[nb].y, w[25], u3);
            u0 = fmaf(xa[nb].z, w[2],  u0); u1 = fmaf(xa[nb].z, w[10], u1);
            u2 = fmaf(xa[nb].z, w[18], u2); u3 = fmaf(xa[nb].z, w[26], u3);
            u0 = fmaf(xa[nb].w, w[3],  u0); u1 = fmaf(xa[nb].w, w[11], u1);
            u2 = fmaf(xa[nb].w, w[19], u2); u3 = fmaf(xa[nb].w, w[27], u3);
            u0 = fmaf(xb[nb].x, w[4],  u0); u1 = fmaf(xb[nb].x, w[12], u1);
            u2 = fmaf(xb[nb].x, w[20], u2); u3 = fmaf(xb[nb].x, w[28], u3);
            u0 = fmaf(xb[nb].y, w[5],  u0); u1 = fmaf(xb[nb].y, w[13], u1);
            u2 = fmaf(xb[nb].y, w[21], u2); u3 = fmaf(xb[nb].y, w[29], u3);
            u0 = fmaf(xb[nb].z, w[6],  u0); u1 = fmaf(xb[nb].z, w[14], u1);
            u2 = fmaf(xb[nb].z, w[22], u2); u3 = fmaf(xb[nb].z, w[30], u3);
            u0 = fmaf(xb[nb].w, w[7],  u0); u1 = fmaf(xb[nb].w, w[15], u1);
            u2 = fmaf(xb[nb].w, w[23], u2); u3 = fmaf(xb[nb].w, w[31], u3);
            float cw;
            if (USEV == 0) {
                cw = 1.0f / 16.0f;
            } else {
                // agree = u . vprev  (vprev = v1, or v1+v2 for the last pass)
                float ag = u0 * va[nb].x + u1 * va[nb].y
                         + u2 * va[nb].z + u3 * va[nb].w;
                ag += __shfl_xor(ag, 1);   // combine d-quads within the a-group
                ag += __shfl_xor(ag, 2);
                const float blog2 = SM_SCALE * ag;
                // softmax over 16 capsules (4-lane groups); strides 4..32 keep
                // lane bits 0-1 fixed, so replicated values fold once per a.
                float m = blog2;
                m = fmaxf(m, __shfl_xor(m, 4));
                m = fmaxf(m, __shfl_xor(m, 8));
                m = fmaxf(m, __shfl_xor(m, 16));
                m = fmaxf(m, __shfl_xor(m, 32));
                const float e = __builtin_amdgcn_exp2f(blog2 - m);  // v_exp_f32
                float sum = e;
                sum += __shfl_xor(sum, 4);
                sum += __shfl_xor(sum, 8);
                sum += __shfl_xor(sum, 16);
                sum += __shfl_xor(sum, 32);
                cw = __fdividef(e, sum);
            }
            // pack to fp16 in-register, 8B LDS write (2-way bank alias = free)
            const u32 p0 = pack_rtz(cw * u0, cw * u1);
            const u32 p1 = pack_rtz(cw * u2, cw * u3);
            *(uint2*)&lds2[buf][wu][nb][lane * 2] = make_uint2(p0, p1);
        }
    };

    compute_phase(0, 0);
    __syncthreads();
    for (int ph = 0; ph < 32; ++ph) {
        if (ph + 1 < 32) compute_phase(ph + 1, (ph + 1) & 1);
        // reduce buf[ph&1]: all 512 threads, one u32 column each (8 waves deep),
        // f32 accumulate (fp16 accumulation would ~7x the rounding error)
        {
            const int nb  = tid >> 7;     // 0..3
            const int col = tid & 127;    // u32 column
            float s0 = 0.f, s1 = 0.f;
#pragma unroll
            for (int wv = 0; wv < 8; ++wv) {
                const u32 raw = lds2[ph & 1][wv][nb][col];
                s0 += h2lo(raw); s1 += h2hi(raw);
            }
            part[(size_t)blockIdx.x * 16384 + (size_t)(ph * 4 + nb) * 128 + col] =
                pack_rtz(s0, s1);
        }
        __syncthreads();   // seals: reads of buf[ph&1] done; buf[(ph+1)&1] ready
    }
}

// Fused 512-deep partial reduction + squash. Thread = (b, a, d-pair):
// 32768 threads; d-norm via shfl_xor over the 8 d-pair lanes.
template<int ADDP>
__global__ __launch_bounds__(256)
void caps_squash_part(const u32* __restrict__ part, float* __restrict__ vout,
                      const float* __restrict__ vprev)
{
    const int gt = (int)blockIdx.x * 256 + (int)threadIdx.x;  // 0..32767
    const int b  = gt >> 7;
    const int r  = gt & 127;                                  // a*8 + dpair
    const int h  = b >> 7;                                    // b-half
    const int lb = b & 127;                                   // local b in tile
    const u32* pp = part + ((size_t)h * 512) * 16384 + (size_t)lb * 128 + r;
    float f0 = 0.f, f1 = 0.f;
#pragma unroll 8
    for (int ic = 0; ic < 512; ++ic) {
        const u32 raw = pp[(size_t)ic * 16384];
        f0 += h2lo(raw);
        f1 += h2hi(raw);
    }
    float sq = f0 * f0 + f1 * f1;
    sq += __shfl_xor(sq, 1);
    sq += __shfl_xor(sq, 2);
    sq += __shfl_xor(sq, 4);
    const float scale = sq / ((1.0f + sq) * sqrtf(sq + 1e-7f));
    float o0 = f0 * scale, o1 = f1 * scale;
    if (ADDP) {
        const float2 p = *(const float2*)(vprev + (size_t)b * 256 + r * 2);
        o0 += p.x; o1 += p.y;
    }
    *(float2*)(vout + (size_t)b * 256 + r * 2) = make_float2(o0, o1);
}

// ---------------- legacy fallback (round-4, known-good) ----------------
template<int USEV>
__global__ __launch_bounds__(512)
void legacy_pass(const float* __restrict__ x, const float* __restrict__ W,
                 const float* __restrict__ vprev, float* __restrict__ s_rep,
                 int n_rep)
{
    __shared__ float lds[8][4][256];
    const int tid  = threadIdx.x;
    const int wu   = __builtin_amdgcn_readfirstlane(tid >> 6);
    const int lane = tid & 63;
    const int a    = lane >> 2;
    const int dq   = lane & 3;
    const int ichunk = (int)blockIdx.x >> 1;
    const int bhalf  = (int)blockIdx.x & 1;
    const int i0 = ichunk * 32 + wu * 4;
    const int rep = (int)blockIdx.x & (n_rep - 1);
    float* srep = s_rep + (size_t)rep * 65536;

    float w[4][32];
#pragma unroll
    for (int ii = 0; ii < 4; ++ii) {
        const float* wp = W + ((size_t)a * IC + (size_t)(i0 + ii)) * 128 + dq * 32;
#pragma unroll
        for (int q = 0; q < 8; ++q) {
            const float4 f = *(const float4*)(wp + q * 4);
            w[ii][q*4+0]=f.x; w[ii][q*4+1]=f.y; w[ii][q*4+2]=f.z; w[ii][q*4+3]=f.w;
        }
    }
#pragma unroll
    for (int ii = 0; ii < 4; ++ii)
#pragma unroll
        for (int k = 0; k < 32; ++k) asm volatile("" : "+v"(w[ii][k]));

    const int b0 = bhalf * 128;
    for (int ph = 0; ph < 32; ++ph) {
        float sl[4][4];
#pragma unroll
        for (int nb = 0; nb < 4; ++nb) {
            sl[nb][0]=0.f; sl[nb][1]=0.f; sl[nb][2]=0.f; sl[nb][3]=0.f;
            const int b = b0 + ph * 4 + nb;
            float4 va;
            if (USEV)
                va = *(const float4*)(vprev + (((size_t)b * 16 + a) * 16 + dq * 4));
#pragma unroll
            for (int ii = 0; ii < 4; ++ii) {
                const float* xp = x + ((size_t)b * IC + (size_t)(i0 + ii)) * 8;
                const float4 xa = *(const float4*)(xp);
                const float4 xb = *(const float4*)(xp + 4);
                float u0, u1, u2, u3;
                u0 = xa.x * w[ii][0];  u1 = xa.x * w[ii][8];
                u2 = xa.x * w[ii][16]; u3 = xa.x * w[ii][24];
                u0 = fmaf(xa.y, w[ii][1],  u0); u1 = fmaf(xa.y, w[ii][9],  u1);
                u2 = fmaf(xa.y, w[ii][17], u2); u3 = fmaf(xa.y, w[ii][25], u3);
                u0 = fmaf(xa.z, w[ii][2],  u0); u1 = fmaf(xa.z, w[ii][10], u1);
                u2 = fmaf(xa.z, w[ii][18], u2); u3 = fmaf(xa.z, w[ii][26], u3);
                u0 = fmaf(xa.w, w[ii][3],  u0); u1 = fmaf(xa.w, w[ii][11], u1);
                u2 = fmaf(xa.w, w[ii][19], u2); u3 = fmaf(xa.w, w[ii][27], u3);
                u0 = fmaf(xb.x, w[ii][4],  u0); u1 = fmaf(xb.x, w[ii][12], u1);
                u2 = fmaf(xb.x, w[ii][20], u2); u3 = fmaf(xb.x, w[ii][28], u3);
                u0 = fmaf(xb.y, w[ii][5],  u0); u1 = fmaf(xb.y, w[ii][13], u1);
                u2 = fmaf(xb.y, w[ii][21], u2); u3 = fmaf(xb.y, w[ii][29], u3);
                u0 = fmaf(xb.z, w[ii][6],  u0); u1 = fmaf(xb.z, w[ii][14], u1);
                u2 = fmaf(xb.z, w[ii][22], u2); u3 = fmaf(xb.z, w[ii][30], u3);
                u0 = fmaf(xb.w, w[ii][7],  u0); u1 = fmaf(xb.w, w[ii][15], u1);
                u2 = fmaf(xb.w, w[ii][23], u2); u3 = fmaf(xb.w, w[ii][31], u3);
                float cw;
                if (USEV == 0) {
                    cw = 1.0f / 16.0f;
                } else {
                    float ag = u0*va.x + u1*va.y + u2*va.z + u3*va.w;
                    ag += __shfl_xor(ag, 1);
                    ag += __shfl_xor(ag, 2);
                    const float blog = 4096.0f * ag;
                    float m = blog;
                    m = fmaxf(m, __shfl_xor(m, 4));
                    m = fmaxf(m, __shfl_xor(m, 8));
                    m = fmaxf(m, __shfl_xor(m, 16));
                    m = fmaxf(m, __shfl_xor(m, 32));
                    const float e = __expf(blog - m);
                    float sum = e;
                    sum += __shfl_xor(sum, 4);
                    sum += __shfl_xor(sum, 8);
                    sum += __shfl_xor(sum, 16);
                    sum += __shfl_xor(sum, 32);
                    cw = __fdividef(e, sum);
                }
                sl[nb][0] = fmaf(cw, u0, sl[nb][0]);
                sl[nb][1] = fmaf(cw, u1, sl[nb][1]);
                sl[nb][2] = fmaf(cw, u2, sl[nb][2]);
                sl[nb][3] = fmaf(cw, u3, sl[nb][3]);
            }
        }
#pragma unroll
        for (int nb = 0; nb < 4; ++nb)
            *(float4*)&lds[wu][nb][lane * 4] =
                make_float4(sl[nb][0], sl[nb][1], sl[nb][2], sl[nb][3]);
        __syncthreads();
        if (tid < 256) {
            const int bsel = tid >> 6;
            const int ad4  = (tid & 63) * 4;
            float4 acc = make_float4(0.f, 0.f, 0.f, 0.f);
#pragma unroll
            for (int wv = 0; wv < 8; ++wv) {
                const float4 f = *(const float4*)&lds[wv][bsel][ad4];
                acc.x += f.x; acc.y += f.y; acc.z += f.z; acc.w += f.w;
            }
            float* dst = srep + (size_t)(b0 + ph * 4 + bsel) * 256 + ad4;
            unsafeAtomicAdd(dst + 0, acc.x);
            unsafeAtomicAdd(dst + 1, acc.y);
            unsafeAtomicAdd(dst + 2, acc.z);
            unsafeAtomicAdd(dst + 3, acc.w);
        }
        __syncthreads();
    }
}

template<int ADDP, int ZERO>
__global__ void legacy_squash(float* __restrict__ srep, int n_rep,
                              float* __restrict__ vout, const float* __restrict__ vprev)
{
    const int t = (int)blockIdx.x * 256 + (int)threadIdx.x;
    float4 f0 = make_float4(0.f,0.f,0.f,0.f), f1 = f0, f2 = f0, f3 = f0;
    for (int r = 0; r < n_rep; ++r) {
        float* sp = srep + (size_t)r * 65536 + (size_t)t * 16;
        const float4 a0 = *(const float4*)(sp + 0);
        const float4 a1 = *(const float4*)(sp + 4);
        const float4 a2 = *(const float4*)(sp + 8);
        const float4 a3 = *(const float4*)(sp + 12);
        f0.x+=a0.x; f0.y+=a0.y; f0.z+=a0.z; f0.w+=a0.w;
        f1.x+=a1.x; f1.y+=a1.y; f1.z+=a1.z; f1.w+=a1.w;
        f2.x+=a2.x; f2.y+=a2.y; f2.z+=a2.z; f2.w+=a2.w;
        f3.x+=a3.x; f3.y+=a3.y; f3.z+=a3.z; f3.w+=a3.w;
        if (ZERO) {
            const float4 z = make_float4(0.f,0.f,0.f,0.f);
            *(float4*)(sp+0)=z; *(float4*)(sp+4)=z; *(float4*)(sp+8)=z; *(float4*)(sp+12)=z;
        }
    }
    float sq = f0.x*f0.x+f0.y*f0.y+f0.z*f0.z+f0.w*f0.w
             + f1.x*f1.x+f1.y*f1.y+f1.z*f1.z+f1.w*f1.w
             + f2.x*f2.x+f2.y*f2.y+f2.z*f2.z+f2.w*f2.w
             + f3.x*f3.x+f3.y*f3.y+f3.z*f3.z+f3.w*f3.w;
    const float scale = sq / ((1.0f + sq) * sqrtf(sq + 1e-7f));
    float4 o0, o1, o2, o3;
    o0.x=f0.x*scale; o0.y=f0.y*scale; o0.z=f0.z*scale; o0.w=f0.w*scale;
    o1.x=f1.x*scale; o1.y=f1.y*scale; o1.z=f1.z*scale; o1.w=f1.w*scale;
    o2.x=f2.x*scale; o2.y=f2.y*scale; o2.z=f2.z*scale; o2.w=f2.w*scale;
    o3.x=f3.x*scale; o3.y=f3.y*scale; o3.z=f3.z*scale; o3.w=f3.w*scale;
    if (ADDP) {
        const float* pp = vprev + (size_t)t * 16;
        const float4 p0 = *(const float4*)(pp + 0);
        const float4 p1 = *(const float4*)(pp + 4);
        const float4 p2 = *(const float4*)(pp + 8);
        const float4 p3 = *(const float4*)(pp + 12);
        o0.x+=p0.x; o0.y+=p0.y; o0.z+=p0.z; o0.w+=p0.w;
        o1.x+=p1.x; o1.y+=p1.y; o1.z+=p1.z; o1.w+=p1.w;
        o2.x+=p2.x; o2.y+=p2.y; o2.z+=p2.z; o2.w+=p2.w;
        o3.x+=p3.x; o3.y+=p3.y; o3.z+=p3.z; o3.w+=p3.w;
    }
    float* vp = vout + (size_t)t * 16;
    *(float4*)(vp+0)=o0; *(float4*)(vp+4)=o1; *(float4*)(vp+8)=o2; *(float4*)(vp+12)=o3;
}

__global__ void legacy_zero(float* __restrict__ p)
{
    *(float4*)(p + ((size_t)blockIdx.x * 256 + threadIdx.x) * 4) =
        make_float4(0.f, 0.f, 0.f, 0.f);
}

extern "C" void kernel_launch(void* const* d_in, const int* in_sizes, int n_in,
                              void* d_out, int out_size, void* d_ws, size_t ws_size,
                              hipStream_t stream)
{
    const float* x = (const float*)d_in[0];   // [256, 4096, 8]
    const float* W = (const float*)d_in[1];   // [16, 4096, 16, 8]
    float* out = (float*)d_out;               // [256, 16, 16]

    // fp16 partials: 1024 tiles x 16384 u32 = 64 MiB
    const size_t need16 = (size_t)1024 * 16384 * 4 + 2 * 65536 * 4;

    if (ws_size >= need16) {
        u32*  part = (u32*)d_ws;
        float* v1  = (float*)((char*)d_ws + (size_t)1024 * 16384 * 4);
        float* vs  = v1 + 65536;
        caps_pass_part<0><<<1024, 512, 0, stream>>>(x, W, nullptr, part);
        caps_squash_part<0><<<128, 256, 0, stream>>>(part, v1, nullptr);
        caps_pass_part<1><<<1024, 512, 0, stream>>>(x, W, v1, part);
        caps_squash_part<1><<<128, 256, 0, stream>>>(part, vs, v1);
        caps_pass_part<1><<<1024, 512, 0, stream>>>(x, W, vs, part);
        caps_squash_part<0><<<128, 256, 0, stream>>>(part, out, nullptr);
    } else {
        int R = 1;
        if (ws_size >= (size_t)(8 + 2) * 65536 * 4) R = 8;
        else if (ws_size >= (size_t)(2 + 2) * 65536 * 4) R = 2;
        float* srep = (float*)d_ws;
        float* v1   = srep + (size_t)R * 65536;
        float* vs   = v1 + 65536;
        legacy_zero<<<R * 64, 256, 0, stream>>>(srep);
        legacy_pass<0><<<256, 512, 0, stream>>>(x, W, nullptr, srep, R);
        legacy_squash<0, 1><<<16, 256, 0, stream>>>(srep, R, v1, nullptr);
        legacy_pass<1><<<256, 512, 0, stream>>>(x, W, v1, srep, R);
        legacy_squash<1, 1><<<16, 256, 0, stream>>>(srep, R, vs, v1);
        legacy_pass<1><<<256, 512, 0, stream>>>(x, W, vs, srep, R);
        legacy_squash<0, 0><<<16, 256, 0, stream>>>(srep, R, out, nullptr);
    }
}

// Round 13
// 484.963 us; speedup vs baseline: 1.1708x; 1.0580x over previous
//
#include <hip/hip_runtime.h>

#define IC 4096
typedef unsigned short u16;
typedef unsigned int   u32;
typedef __fp16 h2 __attribute__((ext_vector_type(2)));   // cvt_pkrtz return type

static __device__ __forceinline__ u32 pack_rtz(float a, float b) {
    h2 h = __builtin_amdgcn_cvt_pkrtz(a, b);   // v_cvt_pkrtz_f16_f32
    u32 u; __builtin_memcpy(&u, &h, 4); return u;
}
static __device__ __forceinline__ float h2lo(u32 r) {
    h2 h; __builtin_memcpy(&h, &r, 4); return (float)h.x;
}
static __device__ __forceinline__ float h2hi(u32 r) {
    h2 h; __builtin_memcpy(&h, &r, 4); return (float)h.y;
}

// ---------------- primary path: r8 skeleton + fp16 global partials ----------
// Grid = 1024 blocks: (i-chunk 0..511) x (b-half). Block = 8 waves = 8 i,
// loops 128 b in 32 phases of 4 (4-way ILP, the r7->r8 +25% lever).
// LDS stays f32 (r12's fp16 LDS pack/unpack added VALU for zero gain);
// partials are packed to fp16 ONCE at the global store (single rounding).
template<int USEV>
__global__ __launch_bounds__(512)
void caps_pass_part(const float* __restrict__ x, const float* __restrict__ W,
                    const float* __restrict__ vprev, u32* __restrict__ part)
{
    __shared__ float lds[8][4][256];
    const int tid  = threadIdx.x;
    const int wu   = __builtin_amdgcn_readfirstlane(tid >> 6);  // wave 0..7
    const int lane = tid & 63;
    const int a    = lane >> 2;   // capsule 0..15
    const int dq   = lane & 3;    // d-quad: lane owns d = dq*4..dq*4+3
    const int ib   = (int)blockIdx.x & 511;   // i-chunk
    const int bh   = (int)blockIdx.x >> 9;    // b-half
    const int i    = ib * 8 + wu;             // this wave's i

    // W cache: 32 floats/lane -- the proven-safe residency size (r7-r12).
    float w[32];
    {
        const float* wp = W + ((size_t)a * IC + i) * 128 + dq * 32;
#pragma unroll
        for (int q = 0; q < 8; ++q) {
            const float4 f = *(const float4*)(wp + q * 4);
            w[q*4+0] = f.x; w[q*4+1] = f.y; w[q*4+2] = f.z; w[q*4+3] = f.w;
        }
    }
#pragma unroll
    for (int k = 0; k < 32; ++k) asm volatile("" : "+v"(w[k]));  // no remat

    const int b0 = bh * 128;
    const float SM_SCALE = 4096.0f * 1.44269504088896f;  // logits in log2 units

    for (int ph = 0; ph < 32; ++ph) {
        // prefetch all 4 b's inputs (independent; x is wave-uniform -> s_load)
        float4 xa[4], xb[4], va[4];
#pragma unroll
        for (int nb = 0; nb < 4; ++nb) {
            const int b = b0 + ph * 4 + nb;
            const float* xp = x + ((size_t)b * IC + i) * 8;
            xa[nb] = *(const float4*)(xp);
            xb[nb] = *(const float4*)(xp + 4);
            if (USEV)
                va[nb] = *(const float4*)(vprev + (((size_t)b * 16 + a) * 16 + dq * 4));
        }
#pragma unroll
        for (int nb = 0; nb < 4; ++nb) {
            float u0, u1, u2, u3;
            u0 = xa[nb].x * w[0];
            u1 = xa[nb].x * w[8];
            u2 = xa[nb].x * w[16];
            u3 = xa[nb].x * w[24];
            u0 = fmaf(xa[nb].y, w[1],  u0); u1 = fmaf(xa[nb].y, w[9],  u1);
            u2 = fmaf(xa[nb].y, w[17], u2); u3 = fmaf(xa[nb].y, w[25], u3);
            u0 = fmaf(xa[nb].z, w[2],  u0); u1 = fmaf(xa[nb].z, w[10], u1);
            u2 = fmaf(xa[nb].z, w[18], u2); u3 = fmaf(xa[nb].z, w[26], u3);
            u0 = fmaf(xa[nb].w, w[3],  u0); u1 = fmaf(xa[nb].w, w[11], u1);
            u2 = fmaf(xa[nb].w, w[19], u2); u3 = fmaf(xa[nb].w, w[27], u3);
            u0 = fmaf(xb[nb].x, w[4],  u0); u1 = fmaf(xb[nb].x, w[12], u1);
            u2 = fmaf(xb[nb].x, w[20], u2); u3 = fmaf(xb[nb].x, w[28], u3);
            u0 = fmaf(xb[nb].y, w[5],  u0); u1 = fmaf(xb[nb].y, w[13], u1);
            u2 = fmaf(xb[nb].y, w[21], u2); u3 = fmaf(xb[nb].y, w[29], u3);
            u0 = fmaf(xb[nb].z, w[6],  u0); u1 = fmaf(xb[nb].z, w[14], u1);
            u2 = fmaf(xb[nb].z, w[22], u2); u3 = fmaf(xb[nb].z, w[30], u3);
            u0 = fmaf(xb[nb].w, w[7],  u0); u1 = fmaf(xb[nb].w, w[15], u1);
            u2 = fmaf(xb[nb].w, w[23], u2); u3 = fmaf(xb[nb].w, w[31], u3);
            float cw;
            if (USEV == 0) {
                cw = 1.0f / 16.0f;
            } else {
                // agree = u . vprev  (vprev = v1, or v1+v2 for the last pass)
                float ag = u0 * va[nb].x + u1 * va[nb].y
                         + u2 * va[nb].z + u3 * va[nb].w;
                ag += __shfl_xor(ag, 1);   // combine d-quads within the a-group
                ag += __shfl_xor(ag, 2);
                const float blog2 = SM_SCALE * ag;
                // softmax over 16 capsules (4-lane groups); strides 4..32 keep
                // lane bits 0-1 fixed, so replicated values fold once per a.
                float m = blog2;
                m = fmaxf(m, __shfl_xor(m, 4));
                m = fmaxf(m, __shfl_xor(m, 8));
                m = fmaxf(m, __shfl_xor(m, 16));
                m = fmaxf(m, __shfl_xor(m, 32));
                const float e = __builtin_amdgcn_exp2f(blog2 - m);  // v_exp_f32
                float sum = e;
                sum += __shfl_xor(sum, 4);
                sum += __shfl_xor(sum, 8);
                sum += __shfl_xor(sum, 16);
                sum += __shfl_xor(sum, 32);
                cw = __fdividef(e, sum);
            }
            // f32 straight to LDS (ds_write_b128: measured conflict-free)
            *(float4*)&lds[wu][nb][lane * 4] =
                make_float4(cw * u0, cw * u1, cw * u2, cw * u3);
        }
        __syncthreads();
        // reduce: ALL 512 threads; thread = (nb, u32-col). float2 over 8 waves,
        // pack to fp16 once (the single rounding), store coalesced.
        {
            const int nb  = tid >> 7;     // 0..3
            const int col = tid & 127;    // output u32 column
            float s0 = 0.f, s1 = 0.f;
#pragma unroll
            for (int wv = 0; wv < 8; ++wv) {
                const float2 f = *(const float2*)&lds[wv][nb][col * 2];
                s0 += f.x; s1 += f.y;
            }
            part[(size_t)blockIdx.x * 16384 + (size_t)(ph * 4 + nb) * 128 + col] =
                pack_rtz(s0, s1);
        }
        __syncthreads();
    }
}

// Fused 512-deep partial reduction + squash. Thread = (b, a, d-pair):
// 32768 threads; d-norm via shfl_xor over the 8 d-pair lanes.
template<int ADDP>
__global__ __launch_bounds__(256)
void caps_squash_part(const u32* __restrict__ part, float* __restrict__ vout,
                      const float* __restrict__ vprev)
{
    const int gt = (int)blockIdx.x * 256 + (int)threadIdx.x;  // 0..32767
    const int b  = gt >> 7;
    const int r  = gt & 127;                                  // a*8 + dpair
    const int h  = b >> 7;                                    // b-half
    const int lb = b & 127;                                   // local b in tile
    const u32* pp = part + ((size_t)h * 512) * 16384 + (size_t)lb * 128 + r;
    float f0 = 0.f, f1 = 0.f;
#pragma unroll 8
    for (int ic = 0; ic < 512; ++ic) {
        const u32 raw = pp[(size_t)ic * 16384];
        f0 += h2lo(raw);
        f1 += h2hi(raw);
    }
    float sq = f0 * f0 + f1 * f1;
    sq += __shfl_xor(sq, 1);
    sq += __shfl_xor(sq, 2);
    sq += __shfl_xor(sq, 4);
    const float scale = sq / ((1.0f + sq) * sqrtf(sq + 1e-7f));
    float o0 = f0 * scale, o1 = f1 * scale;
    if (ADDP) {
        const float2 p = *(const float2*)(vprev + (size_t)b * 256 + r * 2);
        o0 += p.x; o1 += p.y;
    }
    *(float2*)(vout + (size_t)b * 256 + r * 2) = make_float2(o0, o1);
}

// ---------------- legacy fallback (round-4, known-good) ----------------
template<int USEV>
__global__ __launch_bounds__(512)
void legacy_pass(const float* __restrict__ x, const float* __restrict__ W,
                 const float* __restrict__ vprev, float* __restrict__ s_rep,
                 int n_rep)
{
    __shared__ float lds[8][4][256];
    const int tid  = threadIdx.x;
    const int wu   = __builtin_amdgcn_readfirstlane(tid >> 6);
    const int lane = tid & 63;
    const int a    = lane >> 2;
    const int dq   = lane & 3;
    const int ichunk = (int)blockIdx.x >> 1;
    const int bhalf  = (int)blockIdx.x & 1;
    const int i0 = ichunk * 32 + wu * 4;
    const int rep = (int)blockIdx.x & (n_rep - 1);
    float* srep = s_rep + (size_t)rep * 65536;

    float w[4][32];
#pragma unroll
    for (int ii = 0; ii < 4; ++ii) {
        const float* wp = W + ((size_t)a * IC + (size_t)(i0 + ii)) * 128 + dq * 32;
#pragma unroll
        for (int q = 0; q < 8; ++q) {
            const float4 f = *(const float4*)(wp + q * 4);
            w[ii][q*4+0]=f.x; w[ii][q*4+1]=f.y; w[ii][q*4+2]=f.z; w[ii][q*4+3]=f.w;
        }
    }
#pragma unroll
    for (int ii = 0; ii < 4; ++ii)
#pragma unroll
        for (int k = 0; k < 32; ++k) asm volatile("" : "+v"(w[ii][k]));

    const int b0 = bhalf * 128;
    for (int ph = 0; ph < 32; ++ph) {
        float sl[4][4];
#pragma unroll
        for (int nb = 0; nb < 4; ++nb) {
            sl[nb][0]=0.f; sl[nb][1]=0.f; sl[nb][2]=0.f; sl[nb][3]=0.f;
            const int b = b0 + ph * 4 + nb;
            float4 va;
            if (USEV)
                va = *(const float4*)(vprev + (((size_t)b * 16 + a) * 16 + dq * 4));
#pragma unroll
            for (int ii = 0; ii < 4; ++ii) {
                const float* xp = x + ((size_t)b * IC + (size_t)(i0 + ii)) * 8;
                const float4 xa = *(const float4*)(xp);
                const float4 xb = *(const float4*)(xp + 4);
                float u0, u1, u2, u3;
                u0 = xa.x * w[ii][0];  u1 = xa.x * w[ii][8];
                u2 = xa.x * w[ii][16]; u3 = xa.x * w[ii][24];
                u0 = fmaf(xa.y, w[ii][1],  u0); u1 = fmaf(xa.y, w[ii][9],  u1);
                u2 = fmaf(xa.y, w[ii][17], u2); u3 = fmaf(xa.y, w[ii][25], u3);
                u0 = fmaf(xa.z, w[ii][2],  u0); u1 = fmaf(xa.z, w[ii][10], u1);
                u2 = fmaf(xa.z, w[ii][18], u2); u3 = fmaf(xa.z, w[ii][26], u3);
                u0 = fmaf(xa.w, w[ii][3],  u0); u1 = fmaf(xa.w, w[ii][11], u1);
                u2 = fmaf(xa.w, w[ii][19], u2); u3 = fmaf(xa.w, w[ii][27], u3);
                u0 = fmaf(xb.x, w[ii][4],  u0); u1 = fmaf(xb.x, w[ii][12], u1);
                u2 = fmaf(xb.x, w[ii][20], u2); u3 = fmaf(xb.x, w[ii][28], u3);
                u0 = fmaf(xb.y, w[ii][5],  u0); u1 = fmaf(xb.y, w[ii][13], u1);
                u2 = fmaf(xb.y, w[ii][21], u2); u3 = fmaf(xb.y, w[ii][29], u3);
                u0 = fmaf(xb.z, w[ii][6],  u0); u1 = fmaf(xb.z, w[ii][14], u1);
                u2 = fmaf(xb.z, w[ii][22], u2); u3 = fmaf(xb.z, w[ii][30], u3);
                u0 = fmaf(xb.w, w[ii][7],  u0); u1 = fmaf(xb.w, w[ii][15], u1);
                u2 = fmaf(xb.w, w[ii][23], u2); u3 = fmaf(xb.w, w[ii][31], u3);
                float cw;
                if (USEV == 0) {
                    cw = 1.0f / 16.0f;
                } else {
                    float ag = u0*va.x + u1*va.y + u2*va.z + u3*va.w;
                    ag += __shfl_xor(ag, 1);
                    ag += __shfl_xor(ag, 2);
                    const float blog = 4096.0f * ag;
                    float m = blog;
                    m = fmaxf(m, __shfl_xor(m, 4));
                    m = fmaxf(m, __shfl_xor(m, 8));
                    m = fmaxf(m, __shfl_xor(m, 16));
                    m = fmaxf(m, __shfl_xor(m, 32));
                    const float e = __expf(blog - m);
                    float sum = e;
                    sum += __shfl_xor(sum, 4);
                    sum += __shfl_xor(sum, 8);
                    sum += __shfl_xor(sum, 16);
                    sum += __shfl_xor(sum, 32);
                    cw = __fdividef(e, sum);
                }
                sl[nb][0] = fmaf(cw, u0, sl[nb][0]);
                sl[nb][1] = fmaf(cw, u1, sl[nb][1]);
                sl[nb][2] = fmaf(cw, u2, sl[nb][2]);
                sl[nb][3] = fmaf(cw, u3, sl[nb][3]);
            }
        }
#pragma unroll
        for (int nb = 0; nb < 4; ++nb)
            *(float4*)&lds[wu][nb][lane * 4] =
                make_float4(sl[nb][0], sl[nb][1], sl[nb][2], sl[nb][3]);
        __syncthreads();
        if (tid < 256) {
            const int bsel = tid >> 6;
            const int ad4  = (tid & 63) * 4;
            float4 acc = make_float4(0.f, 0.f, 0.f, 0.f);
#pragma unroll
            for (int wv = 0; wv < 8; ++wv) {
                const float4 f = *(const float4*)&lds[wv][bsel][ad4];
                acc.x += f.x; acc.y += f.y; acc.z += f.z; acc.w += f.w;
            }
            float* dst = srep + (size_t)(b0 + ph * 4 + bsel) * 256 + ad4;
            unsafeAtomicAdd(dst + 0, acc.x);
            unsafeAtomicAdd(dst + 1, acc.y);
            unsafeAtomicAdd(dst + 2, acc.z);
            unsafeAtomicAdd(dst + 3, acc.w);
        }
        __syncthreads();
    }
}

template<int ADDP, int ZERO>
__global__ void legacy_squash(float* __restrict__ srep, int n_rep,
                              float* __restrict__ vout, const float* __restrict__ vprev)
{
    const int t = (int)blockIdx.x * 256 + (int)threadIdx.x;
    float4 f0 = make_float4(0.f,0.f,0.f,0.f), f1 = f0, f2 = f0, f3 = f0;
    for (int r = 0; r < n_rep; ++r) {
        float* sp = srep + (size_t)r * 65536 + (size_t)t * 16;
        const float4 a0 = *(const float4*)(sp + 0);
        const float4 a1 = *(const float4*)(sp + 4);
        const float4 a2 = *(const float4*)(sp + 8);
        const float4 a3 = *(const float4*)(sp + 12);
        f0.x+=a0.x; f0.y+=a0.y; f0.z+=a0.z; f0.w+=a0.w;
        f1.x+=a1.x; f1.y+=a1.y; f1.z+=a1.z; f1.w+=a1.w;
        f2.x+=a2.x; f2.y+=a2.y; f2.z+=a2.z; f2.w+=a2.w;
        f3.x+=a3.x; f3.y+=a3.y; f3.z+=a3.z; f3.w+=a3.w;
        if (ZERO) {
            const float4 z = make_float4(0.f,0.f,0.f,0.f);
            *(float4*)(sp+0)=z; *(float4*)(sp+4)=z; *(float4*)(sp+8)=z; *(float4*)(sp+12)=z;
        }
    }
    float sq = f0.x*f0.x+f0.y*f0.y+f0.z*f0.z+f0.w*f0.w
             + f1.x*f1.x+f1.y*f1.y+f1.z*f1.z+f1.w*f1.w
             + f2.x*f2.x+f2.y*f2.y+f2.z*f2.z+f2.w*f2.w
             + f3.x*f3.x+f3.y*f3.y+f3.z*f3.z+f3.w*f3.w;
    const float scale = sq / ((1.0f + sq) * sqrtf(sq + 1e-7f));
    float4 o0, o1, o2, o3;
    o0.x=f0.x*scale; o0.y=f0.y*scale; o0.z=f0.z*scale; o0.w=f0.w*scale;
    o1.x=f1.x*scale; o1.y=f1.y*scale; o1.z=f1.z*scale; o1.w=f1.w*scale;
    o2.x=f2.x*scale; o2.y=f2.y*scale; o2.z=f2.z*scale; o2.w=f2.w*scale;
    o3.x=f3.x*scale; o3.y=f3.y*scale; o3.z=f3.z*scale; o3.w=f3.w*scale;
    if (ADDP) {
        const float* pp = vprev + (size_t)t * 16;
        const float4 p0 = *(const float4*)(pp + 0);
        const float4 p1 = *(const float4*)(pp + 4);
        const float4 p2 = *(const float4*)(pp + 8);
        const float4 p3 = *(const float4*)(pp + 12);
        o0.x+=p0.x; o0.y+=p0.y; o0.z+=p0.z; o0.w+=p0.w;
        o1.x+=p1.x; o1.y+=p1.y; o1.z+=p1.z; o1.w+=p1.w;
        o2.x+=p2.x; o2.y+=p2.y; o2.z+=p2.z; o2.w+=p2.w;
        o3.x+=p3.x; o3.y+=p3.y; o3.z+=p3.z; o3.w+=p3.w;
    }
    float* vp = vout + (size_t)t * 16;
    *(float4*)(vp+0)=o0; *(float4*)(vp+4)=o1; *(float4*)(vp+8)=o2; *(float4*)(vp+12)=o3;
}

__global__ void legacy_zero(float* __restrict__ p)
{
    *(float4*)(p + ((size_t)blockIdx.x * 256 + threadIdx.x) * 4) =
        make_float4(0.f, 0.f, 0.f, 0.f);
}

extern "C" void kernel_launch(void* const* d_in, const int* in_sizes, int n_in,
                              void* d_out, int out_size, void* d_ws, size_t ws_size,
                              hipStream_t stream)
{
    const float* x = (const float*)d_in[0];   // [256, 4096, 8]
    const float* W = (const float*)d_in[1];   // [16, 4096, 16, 8]
    float* out = (float*)d_out;               // [256, 16, 16]

    // fp16 partials: 1024 tiles x 16384 u32 = 64 MiB
    const size_t need16 = (size_t)1024 * 16384 * 4 + 2 * 65536 * 4;

    if (ws_size >= need16) {
        u32*  part = (u32*)d_ws;
        float* v1  = (float*)((char*)d_ws + (size_t)1024 * 16384 * 4);
        float* vs  = v1 + 65536;
        caps_pass_part<0><<<1024, 512, 0, stream>>>(x, W, nullptr, part);
        caps_squash_part<0><<<128, 256, 0, stream>>>(part, v1, nullptr);
        caps_pass_part<1><<<1024, 512, 0, stream>>>(x, W, v1, part);
        caps_squash_part<1><<<128, 256, 0, stream>>>(part, vs, v1);
        caps_pass_part<1><<<1024, 512, 0, stream>>>(x, W, vs, part);
        caps_squash_part<0><<<128, 256, 0, stream>>>(part, out, nullptr);
    } else {
        int R = 1;
        if (ws_size >= (size_t)(8 + 2) * 65536 * 4) R = 8;
        else if (ws_size >= (size_t)(2 + 2) * 65536 * 4) R = 2;
        float* srep = (float*)d_ws;
        float* v1   = srep + (size_t)R * 65536;
        float* vs   = v1 + 65536;
        legacy_zero<<<R * 64, 256, 0, stream>>>(srep);
        legacy_pass<0><<<256, 512, 0, stream>>>(x, W, nullptr, srep, R);
        legacy_squash<0, 1><<<16, 256, 0, stream>>>(srep, R, v1, nullptr);
        legacy_pass<1><<<256, 512, 0, stream>>>(x, W, v1, srep, R);
        legacy_squash<1, 1><<<16, 256, 0, stream>>>(srep, R, vs, v1);
        legacy_pass<1><<<256, 512, 0, stream>>>(x, W, vs, srep, R);
        legacy_squash<0, 0><<<16, 256, 0, stream>>>(srep, R, out, nullptr);
    }
}